// Round 2
// baseline (1596.031 us; speedup 1.0000x reference)
//
#include <hip/hip_runtime.h>
#include <hip/hip_bf16.h>

// Problem dims (fixed by reference): D=512, B=32, S_c=256, S_q(T)=32
#define DIMD 512
#define NB   32
#define NS   256
#define NT   32

typedef __bf16 bf16x8 __attribute__((ext_vector_type(8)));
typedef float  f32x4  __attribute__((ext_vector_type(4)));

__device__ __forceinline__ float tanh_fast(float x) {
    float e = __expf(2.f * x);
    return 1.f - 2.f / (e + 1.f);
}

// ---------------- prep kernels ----------------

// A_cat[b*256+s][0:512]=context[s][b][:], [512:1024]=image[s][b][:]  (fp32 -> bf16)
__global__ void k_prep_acat(const float* __restrict__ ctxin, const float* __restrict__ img,
                            __bf16* __restrict__ acat) {
    int row = blockIdx.x;           // b*256+s
    int b = row >> 8, s = row & 255;
    const float* c  = ctxin + ((size_t)s * NB + b) * DIMD;
    const float* im = img   + ((size_t)s * NB + b) * DIMD;
    __bf16* o = acat + (size_t)row * 1024;
    for (int d = threadIdx.x; d < DIMD; d += 256) {
        o[d]       = (__bf16)c[d];
        o[512 + d] = (__bf16)im[d];
    }
}

__global__ void k_cvt_bf16(const float* __restrict__ in, __bf16* __restrict__ out, int n) {
    for (int i = blockIdx.x * blockDim.x + threadIdx.x; i < n; i += gridDim.x * blockDim.x)
        out[i] = (__bf16)in[i];
}

// dst[c][dOff + r] = src[r][c]  (512x512 fp32 -> bf16 transpose), dst row stride dstStride
__global__ void k_transpose_w(const float* __restrict__ src, __bf16* __restrict__ dst,
                              int dstStride, int dOff) {
    __shared__ float tile[32][33];
    int c0 = blockIdx.x * 32, r0 = blockIdx.y * 32;
    int x = threadIdx.x, y = threadIdx.y;   // x:0..31, y:0..7
#pragma unroll
    for (int k = 0; k < 32; k += 8)
        tile[y + k][x] = src[(size_t)(r0 + y + k) * DIMD + c0 + x];
    __syncthreads();
#pragma unroll
    for (int k = 0; k < 32; k += 8)
        dst[(size_t)(c0 + y + k) * dstStride + dOff + r0 + x] = (__bf16)tile[x][y + k];
}

// ---------------- bf16 MFMA GEMM: C[M,N] = A[M,K] * BT[N,K]^T + bias1 (+bias2) ----------------
// block = 256 threads = 4 waves; block tile 128x128; wave tile 64x64 (4x4 of 16x16x32 MFMA)
__global__ void k_gemm_bt(const __bf16* __restrict__ A, const __bf16* __restrict__ BT,
                          const float* __restrict__ bias1, const float* __restrict__ bias2,
                          void* __restrict__ out, int M, int N, int K, int out_is_f32) {
    int wave = threadIdx.x >> 6, lane = threadIdx.x & 63;
    int wm = wave >> 1, wn = wave & 1;
    int m0 = blockIdx.x * 128 + wm * 64;
    int n0 = blockIdx.y * 128 + wn * 64;
    int lr = lane & 15, lq = lane >> 4;

    f32x4 acc[4][4];
#pragma unroll
    for (int i = 0; i < 4; i++)
#pragma unroll
        for (int j = 0; j < 4; j++) acc[i][j] = (f32x4){0.f, 0.f, 0.f, 0.f};

    const __bf16* apb = A  + (size_t)(m0 + lr) * K + lq * 8;
    const __bf16* bpb = BT + (size_t)(n0 + lr) * K + lq * 8;
    for (int kk = 0; kk < K; kk += 32) {
        bf16x8 af[4], bfv[4];
#pragma unroll
        for (int i = 0; i < 4; i++) af[i]  = *(const bf16x8*)(apb + kk + (size_t)i * 16 * K);
#pragma unroll
        for (int j = 0; j < 4; j++) bfv[j] = *(const bf16x8*)(bpb + kk + (size_t)j * 16 * K);
#pragma unroll
        for (int i = 0; i < 4; i++)
#pragma unroll
            for (int j = 0; j < 4; j++)
                acc[i][j] = __builtin_amdgcn_mfma_f32_16x16x32_bf16(af[i], bfv[j], acc[i][j], 0, 0, 0);
    }

#pragma unroll
    for (int i = 0; i < 4; i++)
#pragma unroll
        for (int j = 0; j < 4; j++) {
            int col = n0 + j * 16 + lr;
            float bs = bias1[col] + (bias2 ? bias2[col] : 0.f);
#pragma unroll
            for (int r = 0; r < 4; r++) {
                int row = m0 + i * 16 + lq * 4 + r;   // verified C/D layout
                float v = acc[i][j][r] + bs;
                if (out_is_f32) ((float*)out)[(size_t)row * N + col] = v;
                else            ((__bf16*)out)[(size_t)row * N + col] = (__bf16)v;
            }
        }
}

// ---------------- scan kernels ----------------

// rm0 = b_rm (r=0), rrt0 = tanh(b_rr)
__global__ void k_init(const float* __restrict__ brm, const float* __restrict__ brr,
                       float* __restrict__ rm, float* __restrict__ rrt) {
    int b = blockIdx.x, e = threadIdx.x;
    rm[b * DIMD + e]  = brm[e];
    rrt[b * DIMD + e] = tanh_fast(brr[e]);
}

// logits[b*256+s] = sum_e tanh(ctx_dm[b,s,e] + rm[b,e] + qm[t,b,e]) * wms[e]
// one wave per (b,s) row; lane covers 8 consecutive e
__global__ void k_logits(const __bf16* __restrict__ ctxdm, const float* __restrict__ qm,
                         const float* __restrict__ rm, const float* __restrict__ wms,
                         float* __restrict__ logits, int t) {
    int wave = threadIdx.x >> 6, lane = threadIdx.x & 63;
    int row = blockIdx.x * 4 + wave;   // b*256+s
    int b = row >> 8;
    int e0 = lane * 8;
    bf16x8 cv = *(const bf16x8*)(ctxdm + (size_t)row * DIMD + e0);
    const float* qp = qm + ((size_t)t * NB + b) * DIMD + e0;
    const float* rp = rm + (size_t)b * DIMD + e0;
    const float* wp = wms + e0;
    float acc = 0.f;
#pragma unroll
    for (int j = 0; j < 8; j++) {
        float x = (float)cv[j] + qp[j] + rp[j];
        acc += tanh_fast(x) * wp[j];
    }
#pragma unroll
    for (int off = 32; off; off >>= 1) acc += __shfl_xor(acc, off);
    if (lane == 0) logits[row] = acc;   // b_ms omitted: softmax shift-invariant
}

// per-batch block (512 threads): softmax over s, r_new = sum_s p*ctx + rrt_prev,
// then rm_next = r_new@W_rm + b_rm, rrt_next = tanh(r_new@W_rr + b_rr)
__global__ void k_update(const float* __restrict__ logits, const __bf16* __restrict__ ctx,
                         const float* __restrict__ Wrm, const float* __restrict__ Wrr,
                         const float* __restrict__ brm, const float* __restrict__ brr,
                         float* __restrict__ rm, float* __restrict__ rrt, float* __restrict__ r) {
    __shared__ float sp[256];
    __shared__ float sred[256];
    __shared__ float sr[DIMD];
    int b = blockIdx.x, tid = threadIdx.x;
    if (tid < 256) {
        float e = __expf(logits[b * NS + tid]);   // |logits| small; no max-sub needed
        sp[tid] = e; sred[tid] = e;
    }
    __syncthreads();
    for (int st = 128; st > 0; st >>= 1) {
        if (tid < st) sred[tid] += sred[tid + st];
        __syncthreads();
    }
    float inv = 1.f / sred[0];

    float acc = 0.f;
    const __bf16* cp = ctx + (size_t)b * NS * DIMD + tid;
    for (int s = 0; s < NS; s++) acc += sp[s] * (float)cp[(size_t)s * DIMD];
    float rn = acc * inv + rrt[b * DIMD + tid];
    r[b * DIMD + tid] = rn;
    sr[tid] = rn;
    __syncthreads();

    float a1 = brm[tid], a2 = brr[tid];
    for (int d = 0; d < DIMD; d++) {
        float rv = sr[d];
        a1 += rv * Wrm[d * DIMD + tid];
        a2 += rv * Wrr[d * DIMD + tid];
    }
    rm[b * DIMD + tid]  = a1;
    rrt[b * DIMD + tid] = tanh_fast(a2);
}

// g = r@W_rg + b_rg + qh@W_qg + b_qg
__global__ void k_final(const float* __restrict__ r, const float* __restrict__ qh,
                        const float* __restrict__ Wrg, const float* __restrict__ Wqg,
                        const float* __restrict__ brg, const float* __restrict__ bqg,
                        float* __restrict__ out) {
    int b = blockIdx.x, e = threadIdx.x;
    float acc = brg[e] + bqg[e];
    const float* rp = r + b * DIMD;
    const float* qp = qh + b * DIMD;
    for (int d = 0; d < DIMD; d++)
        acc += rp[d] * Wrg[d * DIMD + e] + qp[d] * Wqg[d * DIMD + e];
    out[b * DIMD + e] = acc;
}

// ---------------- host ----------------

extern "C" void kernel_launch(void* const* d_in, const int* in_sizes, int n_in,
                              void* d_out, int out_size, void* d_ws, size_t ws_size,
                              hipStream_t stream) {
    const float* ctx_in = (const float*)d_in[0];
    const float* q_in   = (const float*)d_in[1];
    const float* qh     = (const float*)d_in[2];
    const float* img    = (const float*)d_in[3];
    const float* W_fc1  = (const float*)d_in[4];
    const float* b_fc1  = (const float*)d_in[5];
    const float* W_fc2  = (const float*)d_in[6];
    const float* b_fc2  = (const float*)d_in[7];
    const float* W_dm   = (const float*)d_in[8];
    const float* b_dm   = (const float*)d_in[9];
    const float* W_rm   = (const float*)d_in[10];
    const float* b_rm   = (const float*)d_in[11];
    const float* W_qm   = (const float*)d_in[12];
    const float* b_qm   = (const float*)d_in[13];
    const float* W_rr   = (const float*)d_in[14];
    const float* b_rr   = (const float*)d_in[15];
    const float* W_rg   = (const float*)d_in[16];
    const float* b_rg   = (const float*)d_in[17];
    const float* W_qg   = (const float*)d_in[18];
    const float* b_qg   = (const float*)d_in[19];
    const float* W_ms   = (const float*)d_in[20];
    // d_in[21] = b_ms: unused (softmax shift-invariant)

    // workspace layout (~38.9 MB total)
    char* w = (char*)d_ws;
    __bf16* acat  = (__bf16*)w;  w += (size_t)8192 * 1024 * 2;   // 16.78 MB
    __bf16* qp    = (__bf16*)w;  w += (size_t)1024 * 512 * 2;    //  1.05 MB
    __bf16* wcatT = (__bf16*)w;  w += (size_t)512 * 1024 * 2;    //  1.05 MB
    __bf16* wdmT  = (__bf16*)w;  w += (size_t)512 * 512 * 2;     //  0.52 MB
    __bf16* wqmT  = (__bf16*)w;  w += (size_t)512 * 512 * 2;     //  0.52 MB
    __bf16* ctxb  = (__bf16*)w;  w += (size_t)8192 * 512 * 2;    //  8.39 MB
    __bf16* ctxdm = (__bf16*)w;  w += (size_t)8192 * 512 * 2;    //  8.39 MB
    float*  qmf   = (float*)w;   w += (size_t)1024 * 512 * 4;    //  2.10 MB
    float*  rm    = (float*)w;   w += (size_t)NB * DIMD * 4;
    float*  rrt   = (float*)w;   w += (size_t)NB * DIMD * 4;
    float*  rbuf  = (float*)w;   w += (size_t)NB * DIMD * 4;
    float*  logit = (float*)w;   w += (size_t)NB * NS * 4;

    // prep: layouts + bf16 conversion + W transposes
    k_prep_acat<<<8192, 256, 0, stream>>>(ctx_in, img, acat);
    k_cvt_bf16<<<512, 256, 0, stream>>>(q_in, qp, NT * NB * DIMD);
    k_transpose_w<<<dim3(16, 16), dim3(32, 8), 0, stream>>>(W_fc1, wcatT, 1024, 0);
    k_transpose_w<<<dim3(16, 16), dim3(32, 8), 0, stream>>>(W_fc2, wcatT, 1024, 512);
    k_transpose_w<<<dim3(16, 16), dim3(32, 8), 0, stream>>>(W_dm, wdmT, 512, 0);
    k_transpose_w<<<dim3(16, 16), dim3(32, 8), 0, stream>>>(W_qm, wqmT, 512, 0);

    // big GEMMs (bf16 MFMA)
    k_gemm_bt<<<dim3(64, 4), 256, 0, stream>>>(acat, wcatT, b_fc1, b_fc2, ctxb, 8192, 512, 1024, 0);
    k_gemm_bt<<<dim3(64, 4), 256, 0, stream>>>(ctxb, wdmT, b_dm, nullptr, ctxdm, 8192, 512, 512, 0);
    k_gemm_bt<<<dim3(8, 4), 256, 0, stream>>>(qp, wqmT, b_qm, nullptr, qmf, 1024, 512, 512, 1);

    // scan
    k_init<<<NB, DIMD, 0, stream>>>(b_rm, b_rr, rm, rrt);
    for (int t = 0; t < NT; t++) {
        k_logits<<<2048, 256, 0, stream>>>(ctxdm, qmf, rm, W_ms, logit, t);
        k_update<<<NB, DIMD, 0, stream>>>(logit, ctxb, W_rm, W_rr, b_rm, b_rr, rm, rrt, rbuf);
    }
    k_final<<<NB, DIMD, 0, stream>>>(rbuf, qh, W_rg, W_qg, b_rg, b_qg, (float*)d_out);
}